// Round 5
// baseline (15531.987 us; speedup 1.0000x reference)
//
#include <hip/hip_runtime.h>
#include <hip/hip_bf16.h>
#include <cstdint>

// ---------------------------------------------------------------------------
// 2-layer LSTM (B=512, T=128, F=64, H=1024) + dense sigmoid head.
// R5: weights pre-packed into MFMA-fragment-contiguous granules (1 KB per
// 16n x 32k B-fragment) -> B loads are single coalesced dwordx4/lane from
// L2, no LDS. Only A (the sequential h/x activations) is staged via
// global_load_lds into a double-buffered 16 KB LDS tile; one barrier per
// k-tile. B fragments register-double-buffered across k-tiles.
// ---------------------------------------------------------------------------

typedef __attribute__((ext_vector_type(8))) _Float16 half8;
typedef __attribute__((ext_vector_type(4))) _Float16 half4v;
typedef __attribute__((ext_vector_type(4))) float    float4v;

#define AS1 __attribute__((address_space(1)))
#define AS3 __attribute__((address_space(3)))

__device__ __forceinline__ void g2l16(const void* gptr, void* lptr) {
    __builtin_amdgcn_global_load_lds((const AS1 void*)gptr, (AS3 void*)lptr, 16, 0, 0);
}

__device__ __forceinline__ float sigf(float x) { return 1.0f / (1.0f + __expf(-x)); }
__device__ __forceinline__ float tanhfast(float x) { return 2.0f * sigf(2.0f * x) - 1.0f; }

static constexpr size_t HS = 512ull * 1024;   // one h ping-pong slot (elems)

// ---------------------------------------------------------------------------
// Fused pipeline step. Launch s (0..128):
//   blocks [0,256):   layer1 step t=s      (skip when s==128)
//   blocks [256,512): layer2 step t=s-1    (skip when s==0)
// z = [x_t|h] @ [W|U]^T + bias ; gates ; c,h update.
// Block tile 64m x 32n x 4 gates, 4 waves; wave tile 32m x 16n x 4 gates.
// Grid 512 = 2 blocks/CU. XCD = blockIdx%8 follows n-tile low bits -> each
// XCD re-reads a fixed 3.2 MB packed-weight slice (L2-resident).
// Packed B granule (ntG, kc): 64 lanes x 16 B; lane l = unit ntG*16+(l&15),
// k = kc*32 + (l>>4)*8 .. +7  == exactly the mfma_f32_16x16x32_f16 B-frag.
// A LDS: XOR chunk swizzle slot = kc8 ^ (row&7) on the global source side
// (g2l16 LDS dest is lane-forced), ds_read_b128 2-way aliased (= free).
// ---------------------------------------------------------------------------
__global__ __launch_bounds__(256, 2) void fused_step(
    int s,
    const _Float16* __restrict__ xb,
    const _Float16* __restrict__ P1,   // packed layer1 [W1|U1], KC1=34
    const _Float16* __restrict__ P2,   // packed layer2 [W2|U2], KC2=64
    const float* __restrict__ b1, float* __restrict__ c1, _Float16* __restrict__ h1,
    const float* __restrict__ b2, float* __restrict__ c2, _Float16* __restrict__ h2)
{
    __shared__ __align__(16) _Float16 Alds[2][64 * 64];   // [buf][row][slot*8]

    const int role = blockIdx.x >> 8;        // 0: layer1, 1: layer2
    const int idx  = blockIdx.x & 255;

    const _Float16 *A1, *A2, *Pk;
    const float* bias; float* cs; _Float16* ho;
    long a1s, a1o; int KA, KC;
    if (role == 0) {                         // ---- layer 1, step t = s ----
        const int t = s; if (t >= 128) return;
        A1 = xb; a1s = 128 * 64; a1o = (long)t * 64; KA = 64;
        A2 = h1 + (size_t)(t & 1) * HS;      // h1(t-1)
        Pk = P1; KC = 34; bias = b1; cs = c1;
        ho = h1 + (size_t)(1 - (t & 1)) * HS;
    } else {                                 // ---- layer 2, step t = s-1 ----
        const int t = s - 1; if (t < 0) return;
        A1 = h1 + (size_t)(1 - (t & 1)) * HS;  // h1(t), written by launch s-1
        a1s = 1024; a1o = 0; KA = 1024;
        A2 = h2 + (size_t)(t & 1) * HS;      // h2(t-1)
        Pk = P2; KC = 64; bias = b2; cs = c2;
        ho = h2 + (size_t)(1 - (t & 1)) * HS;
    }

    const int tid = threadIdx.x;
    const int w   = tid >> 6;      // wave 0..3
    const int l   = tid & 63;
    const int q   = l >> 4;        // quad 0..3
    const int c16 = l & 15;
    const int mh  = w & 1;         // 32-row half
    const int nh  = w >> 1;        // 16-unit half

    const int m0 = (idx >> 5) * 64;      // 8 m-tiles
    const int n0 = (idx & 31) * 32;      // 32 n-tiles (low bits -> XCD slice)

    const int lr = l >> 3;         // row-in-group 0..7
    const int lc = l & 7;          // chunk slot 0..7
    const int kcg = lc ^ lr;       // swizzled global chunk this lane fetches

    // per-gate packed-B base pointers (granule row = g*64 + n0/16 + nh)
    const _Float16* bp[4];
#pragma unroll
    for (int g = 0; g < 4; ++g)
        bp[g] = Pk + ((size_t)(g * 64 + (n0 >> 4) + nh) * KC) * 512 + (size_t)l * 8;

    float4v acc[4][2] = {};        // [gate][m-subtile]
    const int KT = (KA + 1024) >> 6;   // 17 (L1) / 32 (L2)

    auto stageA = [&](int kt, int p) {
        const int kbase = kt << 6;
        const _Float16* Ap;  long arow, aoff;
        if (kbase < KA) { Ap = A1; arow = a1s;  aoff = a1o + kbase; }
        else            { Ap = A2; arow = 1024; aoff = kbase - KA; }
#pragma unroll
        for (int ii = 0; ii < 2; ++ii) {
            const int i = w + ii * 4;            // row group 0..7
            g2l16(Ap + (long)(m0 + i * 8 + lr) * arow + aoff + kcg * 8,
                  &Alds[p][i * 512]);
        }
    };
    auto loadB = [&](int kt, half8 (&fb)[2][4]) {
#pragma unroll
        for (int K0 = 0; K0 < 2; ++K0)
#pragma unroll
            for (int g = 0; g < 4; ++g)
                fb[K0][g] = *(const half8*)(bp[g] + (size_t)(kt * 2 + K0) * 512);
    };

    const int m1 = mh * 32 + c16;
    const int m2 = m1 + 16;          // (m2&7)==(m1&7)

    half8 fb[2][2][4];               // [reg-buf][K0][gate]
    stageA(0, 0);
    loadB(0, fb[0]);
    __syncthreads();

    for (int kt = 0; kt < KT; ++kt) {
        const int p = kt & 1;
        if (kt + 1 < KT) {
            stageA(kt + 1, p ^ 1);   // overlaps compute below
            loadB(kt + 1, fb[p ^ 1]);
        }
        // ---- compute k-tile kt: A from LDS buf p, B from regs ----
#pragma unroll
        for (int K0 = 0; K0 < 2; ++K0) {
            const int kc8 = K0 * 4 + q;
            const int as = (kc8 ^ (m1 & 7)) * 8;
            half8 af0 = *(const half8*)&Alds[p][m1 * 64 + as];
            half8 af1 = *(const half8*)&Alds[p][m2 * 64 + as];
#pragma unroll
            for (int g = 0; g < 4; ++g) {
                acc[g][0] = __builtin_amdgcn_mfma_f32_16x16x32_f16(af0, fb[p][K0][g], acc[g][0], 0, 0, 0);
                acc[g][1] = __builtin_amdgcn_mfma_f32_16x16x32_f16(af1, fb[p][K0][g], acc[g][1], 0, 0, 0);
            }
        }
        // one barrier/k-tile: drains stageA(kt+1)+loadB(kt+1) (overlapped by
        // the MFMAs above); A reads of buf p done before kt+1 overwrites p^1.
        __syncthreads();
    }

    // ---- fused gate epilogue: D row = quad*4+i, col = lane&15 ----
    const int ng = n0 + nh * 16 + c16;
    const float bi  = bias[ng];
    const float bff = bias[1024 + ng];
    const float bg  = bias[2048 + ng];
    const float bo  = bias[3072 + ng];
#pragma unroll
    for (int mt = 0; mt < 2; ++mt) {
#pragma unroll
        for (int i = 0; i < 4; ++i) {
            const int m = m0 + mh * 32 + mt * 16 + q * 4 + i;
            const float zi = acc[0][mt][i] + bi;
            const float zf = acc[1][mt][i] + bff;
            const float zg = acc[2][mt][i] + bg;
            const float zo = acc[3][mt][i] + bo;
            const float ig = sigf(zi);
            const float fg = sigf(zf);
            const float gg = tanhfast(zg);
            const float og = sigf(zo);
            const size_t id2 = (size_t)m * 1024 + ng;
            const float cc = fg * cs[id2] + ig * gg;
            cs[id2] = cc;
            ho[id2] = (_Float16)(og * tanhfast(cc));
        }
    }
}

// ---------------------------------------------------------------------------
// Pack [W (KA,4096) | U (K-KA,4096)] fp32 row-major into fragment granules:
// out[((ntG*KC + kc)*64 + lane)*8 + j] = f16( src[k][ntG*16+(lane&15)] ),
// k = kc*32 + (lane>>4)*8 + j.  One-time cost per call.
// ---------------------------------------------------------------------------
__global__ void pack_weights(const float* __restrict__ W, const float* __restrict__ U,
                             int KA, int KC, _Float16* __restrict__ out)
{
    const size_t e = (size_t)blockIdx.x * blockDim.x + threadIdx.x;
    const size_t total = (size_t)256 * KC * 512;
    if (e >= total) return;
    const int j    = (int)(e & 7);
    const int lane = (int)((e >> 3) & 63);
    const size_t g = e >> 9;
    const int kc  = (int)(g % KC);
    const int ntG = (int)(g / KC);
    const int col = ntG * 16 + (lane & 15);
    const int k   = kc * 32 + (lane >> 4) * 8 + j;
    const float v = (k < KA) ? W[(size_t)k * 4096 + col]
                             : U[(size_t)(k - KA) * 4096 + col];
    out[e] = (_Float16)v;
}

__global__ void cvt_f16(const float* __restrict__ in, _Float16* __restrict__ out, int n)
{
    int i = (blockIdx.x * blockDim.x + threadIdx.x) * 4;
    if (i + 3 < n) {
        float4 v = *(const float4*)(in + i);
        half4v h = { (_Float16)v.x, (_Float16)v.y, (_Float16)v.z, (_Float16)v.w };
        *(half4v*)(out + i) = h;
    }
}

// ---------------------------------------------------------------------------
// Dense head: out[m] = sigmoid(h2[m,:] . Wd + bd), one wave per row
// ---------------------------------------------------------------------------
__global__ __launch_bounds__(64) void dense_head(const _Float16* __restrict__ h2,
                                                 const float* __restrict__ Wd,
                                                 const float* __restrict__ bd,
                                                 float* __restrict__ out)
{
    const int m = blockIdx.x;
    const int l = threadIdx.x;
    float s = 0.0f;
#pragma unroll
    for (int k = l; k < 1024; k += 64)
        s += (float)h2[(size_t)m * 1024 + k] * Wd[k];
    for (int off = 32; off > 0; off >>= 1) s += __shfl_down(s, off);
    if (l == 0) out[m] = 1.0f / (1.0f + __expf(-(s + bd[0])));
}

// ---------------------------------------------------------------------------

extern "C" void kernel_launch(void* const* d_in, const int* in_sizes, int n_in,
                              void* d_out, int out_size, void* d_ws, size_t ws_size,
                              hipStream_t stream)
{
    const float* x  = (const float*)d_in[0];
    const float* W1 = (const float*)d_in[1];
    const float* U1 = (const float*)d_in[2];
    const float* b1 = (const float*)d_in[3];
    const float* W2 = (const float*)d_in[4];
    const float* U2 = (const float*)d_in[5];
    const float* b2 = (const float*)d_in[6];
    const float* Wd = (const float*)d_in[7];
    const float* bd = (const float*)d_in[8];
    float* out = (float*)d_out;

    char* ws = (char*)d_ws;
    size_t off = 0;
    auto alloc = [&](size_t bytes) {
        char* p = ws + off;
        off = (off + bytes + 255) & ~(size_t)255;
        return p;
    };
    _Float16* xb = (_Float16*)alloc(512ull * 128 * 64 * 2);   // x as f16 (B,T,F)
    _Float16* P1 = (_Float16*)alloc(256ull * 34 * 512 * 2);   // packed layer1
    _Float16* P2 = (_Float16*)alloc(256ull * 64 * 512 * 2);   // packed layer2
    _Float16* h1 = (_Float16*)alloc(2ull * 512 * 1024 * 2);   // ping-pong
    _Float16* h2 = (_Float16*)alloc(2ull * 512 * 1024 * 2);
    float*    c1 = (float*)alloc(512ull * 1024 * 4);
    float*    c2 = (float*)alloc(512ull * 1024 * 4);

    // zero initial state (ws is re-poisoned to 0xAA before every launch)
    hipMemsetAsync(c1, 0, 512ull * 1024 * 4, stream);
    hipMemsetAsync(c2, 0, 512ull * 1024 * 4, stream);
    hipMemsetAsync(h1, 0, 512ull * 1024 * 2, stream);  // slot 0 (read at t=0)
    hipMemsetAsync(h2, 0, 512ull * 1024 * 2, stream);  // slot 0

    cvt_f16<<<4096, 256, 0, stream>>>(x, xb, 512 * 128 * 64);
    pack_weights<<<(256 * 34 * 512 + 255) / 256, 256, 0, stream>>>(W1, U1, 64, 34, P1);
    pack_weights<<<(256 * 64 * 512 + 255) / 256, 256, 0, stream>>>(W2, U2, 1024, 64, P2);

    // 129 pipelined launches: launch s does layer1(s) + layer2(s-1)
    for (int s = 0; s <= 128; ++s) {
        fused_step<<<512, 256, 0, stream>>>(s, xb, P1, P2,
                                            b1, c1, h1, b2, c2, h2);
    }
    // h2(127) lands in slot 0
    dense_head<<<512, 64, 0, stream>>>(h2, Wd, bd, out);
}

// Round 6
// 4008.769 us; speedup vs baseline: 3.8745x; 3.8745x over previous
//
#include <hip/hip_runtime.h>
#include <hip/hip_bf16.h>
#include <cstdint>

// ---------------------------------------------------------------------------
// 2-layer LSTM (B=512, T=128, F=64, H=1024) + dense sigmoid head.
// R6 = R5 (packed-B granules direct from L2, A-only LDS) with the scratch
// spill fixed: the B register double-buffer is two DISTINCT variables in a
// manually 2x-unrolled K-loop (R5 used fb[p] with runtime p -> the array
// went to scratch: 256 MB/launch of spill traffic, VGPR_Count 48).
// ---------------------------------------------------------------------------

typedef __attribute__((ext_vector_type(8))) _Float16 half8;
typedef __attribute__((ext_vector_type(4))) _Float16 half4v;
typedef __attribute__((ext_vector_type(4))) float    float4v;

#define AS1 __attribute__((address_space(1)))
#define AS3 __attribute__((address_space(3)))

__device__ __forceinline__ void g2l16(const void* gptr, void* lptr) {
    __builtin_amdgcn_global_load_lds((const AS1 void*)gptr, (AS3 void*)lptr, 16, 0, 0);
}

__device__ __forceinline__ float sigf(float x) { return 1.0f / (1.0f + __expf(-x)); }
__device__ __forceinline__ float tanhfast(float x) { return 2.0f * sigf(2.0f * x) - 1.0f; }

static constexpr size_t HS = 512ull * 1024;   // one h ping-pong slot (elems)

// ---------------------------------------------------------------------------
// Fused pipeline step. Launch s (0..128):
//   blocks [0,256):   layer1 step t=s      (skip when s==128)
//   blocks [256,512): layer2 step t=s-1    (skip when s==0)
// z = [x_t|h] @ [W|U]^T + bias ; gates ; c,h update.
// Block tile 64m x 32n x 4 gates, 4 waves; wave tile 32m x 16n x 4 gates.
// Grid 512 = 2 blocks/CU. XCD = blockIdx%8 follows n-tile low bits -> each
// XCD re-reads a fixed ~3 MB packed-weight slice (L2-resident).
// Packed B granule (ntG, kc): 64 lanes x 16 B; lane l = unit ntG*16+(l&15),
// k = kc*32 + (l>>4)*8 .. +7  == exactly the mfma_f32_16x16x32_f16 B-frag.
// A LDS: XOR chunk swizzle slot = kc8 ^ (row&7) on the global source side
// (g2l16 LDS dest is lane-forced), ds_read_b128 2-way aliased (= free).
// ---------------------------------------------------------------------------
__global__ __launch_bounds__(256, 2) void fused_step(
    int s,
    const _Float16* __restrict__ xb,
    const _Float16* __restrict__ P1,   // packed layer1 [W1|U1], KC1=34
    const _Float16* __restrict__ P2,   // packed layer2 [W2|U2], KC2=64
    const float* __restrict__ b1, float* __restrict__ c1, _Float16* __restrict__ h1,
    const float* __restrict__ b2, float* __restrict__ c2, _Float16* __restrict__ h2)
{
    __shared__ __align__(16) _Float16 Alds0[64 * 64];   // [row][slot*8]
    __shared__ __align__(16) _Float16 Alds1[64 * 64];

    const int role = blockIdx.x >> 8;        // 0: layer1, 1: layer2
    const int idx  = blockIdx.x & 255;

    const _Float16 *A1, *A2, *Pk;
    const float* bias; float* cs; _Float16* ho;
    long a1s, a1o; int KA, KC;
    if (role == 0) {                         // ---- layer 1, step t = s ----
        const int t = s; if (t >= 128) return;
        A1 = xb; a1s = 128 * 64; a1o = (long)t * 64; KA = 64;
        A2 = h1 + (size_t)(t & 1) * HS;      // h1(t-1)
        Pk = P1; KC = 34; bias = b1; cs = c1;
        ho = h1 + (size_t)(1 - (t & 1)) * HS;
    } else {                                 // ---- layer 2, step t = s-1 ----
        const int t = s - 1; if (t < 0) return;
        A1 = h1 + (size_t)(1 - (t & 1)) * HS;  // h1(t), written by launch s-1
        a1s = 1024; a1o = 0; KA = 1024;
        A2 = h2 + (size_t)(t & 1) * HS;      // h2(t-1)
        Pk = P2; KC = 64; bias = b2; cs = c2;
        ho = h2 + (size_t)(1 - (t & 1)) * HS;
    }

    const int tid = threadIdx.x;
    const int w   = tid >> 6;      // wave 0..3
    const int l   = tid & 63;
    const int q   = l >> 4;        // quad 0..3
    const int c16 = l & 15;
    const int mh  = w & 1;         // 32-row half
    const int nh  = w >> 1;        // 16-unit half

    const int m0 = (idx >> 5) * 64;      // 8 m-tiles
    const int n0 = (idx & 31) * 32;      // 32 n-tiles (low bits -> XCD slice)

    const int lr = l >> 3;         // row-in-group 0..7
    const int lc = l & 7;          // chunk slot 0..7
    const int kcg = lc ^ lr;       // swizzled global chunk this lane fetches

    // per-gate packed-B base pointers (granule row = g*64 + n0/16 + nh)
    const _Float16* bp[4];
#pragma unroll
    for (int g = 0; g < 4; ++g)
        bp[g] = Pk + ((size_t)(g * 64 + (n0 >> 4) + nh) * KC) * 512 + (size_t)l * 8;

    float4v acc[4][2] = {};        // [gate][m-subtile]
    const int KT = (KA + 1024) >> 6;   // 17 (L1) / 32 (L2)

    auto stageA = [&](int kt, _Float16* Ab) {
        const int kbase = kt << 6;
        const _Float16* Ap;  long arow, aoff;
        if (kbase < KA) { Ap = A1; arow = a1s;  aoff = a1o + kbase; }
        else            { Ap = A2; arow = 1024; aoff = kbase - KA; }
#pragma unroll
        for (int ii = 0; ii < 2; ++ii) {
            const int i = w + ii * 4;            // row group 0..7
            g2l16(Ap + (long)(m0 + i * 8 + lr) * arow + aoff + kcg * 8,
                  Ab + i * 512);
        }
    };
    auto loadB = [&](int kt, half8 (&fb)[2][4]) {
#pragma unroll
        for (int K0 = 0; K0 < 2; ++K0)
#pragma unroll
            for (int g = 0; g < 4; ++g)
                fb[K0][g] = *(const half8*)(bp[g] + (size_t)(kt * 2 + K0) * 512);
    };

    const int m1 = mh * 32 + c16;
    const int m2 = m1 + 16;          // (m2&7)==(m1&7)

    auto computeTile = [&](const _Float16* Ab, const half8 (&fb)[2][4]) {
#pragma unroll
        for (int K0 = 0; K0 < 2; ++K0) {
            const int kc8 = K0 * 4 + q;
            const int as = (kc8 ^ (m1 & 7)) * 8;
            half8 af0 = *(const half8*)(Ab + m1 * 64 + as);
            half8 af1 = *(const half8*)(Ab + m2 * 64 + as);
#pragma unroll
            for (int g = 0; g < 4; ++g) {
                acc[g][0] = __builtin_amdgcn_mfma_f32_16x16x32_f16(af0, fb[K0][g], acc[g][0], 0, 0, 0);
                acc[g][1] = __builtin_amdgcn_mfma_f32_16x16x32_f16(af1, fb[K0][g], acc[g][1], 0, 0, 0);
            }
        }
    };

    half8 fb0[2][4], fb1[2][4];      // DISTINCT variables: no dynamic indexing
    stageA(0, Alds0);
    loadB(0, fb0);
    __syncthreads();

    int kt = 0;
    for (; kt + 2 <= KT; kt += 2) {
        // ---- even tile kt: A in Alds0, B in fb0 ----
        stageA(kt + 1, Alds1);
        loadB(kt + 1, fb1);
        computeTile(Alds0, fb0);
        __syncthreads();             // drains stage(kt+1) (overlapped above)
        // ---- odd tile kt+1: A in Alds1, B in fb1 ----
        if (kt + 2 < KT) {
            stageA(kt + 2, Alds0);
            loadB(kt + 2, fb0);
        }
        computeTile(Alds1, fb1);
        __syncthreads();
    }
    if (kt < KT) computeTile(Alds0, fb0);   // odd-KT tail (layer1: KT=17)

    // ---- fused gate epilogue: D row = quad*4+i, col = lane&15 ----
    const int ng = n0 + nh * 16 + c16;
    const float bi  = bias[ng];
    const float bff = bias[1024 + ng];
    const float bg  = bias[2048 + ng];
    const float bo  = bias[3072 + ng];
#pragma unroll
    for (int mt = 0; mt < 2; ++mt) {
#pragma unroll
        for (int i = 0; i < 4; ++i) {
            const int m = m0 + mh * 32 + mt * 16 + q * 4 + i;
            const float zi = acc[0][mt][i] + bi;
            const float zf = acc[1][mt][i] + bff;
            const float zg = acc[2][mt][i] + bg;
            const float zo = acc[3][mt][i] + bo;
            const float ig = sigf(zi);
            const float fg = sigf(zf);
            const float gg = tanhfast(zg);
            const float og = sigf(zo);
            const size_t id2 = (size_t)m * 1024 + ng;
            const float cc = fg * cs[id2] + ig * gg;
            cs[id2] = cc;
            ho[id2] = (_Float16)(og * tanhfast(cc));
        }
    }
}

// ---------------------------------------------------------------------------
// Pack [W (KA,4096) | U (K-KA,4096)] fp32 row-major into fragment granules:
// out[((ntG*KC + kc)*64 + lane)*8 + j] = f16( src[k][ntG*16+(lane&15)] ),
// k = kc*32 + (lane>>4)*8 + j.  One-time cost per call.
// ---------------------------------------------------------------------------
__global__ void pack_weights(const float* __restrict__ W, const float* __restrict__ U,
                             int KA, int KC, _Float16* __restrict__ out)
{
    const size_t e = (size_t)blockIdx.x * blockDim.x + threadIdx.x;
    const size_t total = (size_t)256 * KC * 512;
    if (e >= total) return;
    const int j    = (int)(e & 7);
    const int lane = (int)((e >> 3) & 63);
    const size_t g = e >> 9;
    const int kc  = (int)(g % KC);
    const int ntG = (int)(g / KC);
    const int col = ntG * 16 + (lane & 15);
    const int k   = kc * 32 + (lane >> 4) * 8 + j;
    const float v = (k < KA) ? W[(size_t)k * 4096 + col]
                             : U[(size_t)(k - KA) * 4096 + col];
    out[e] = (_Float16)v;
}

__global__ void cvt_f16(const float* __restrict__ in, _Float16* __restrict__ out, int n)
{
    int i = (blockIdx.x * blockDim.x + threadIdx.x) * 4;
    if (i + 3 < n) {
        float4 v = *(const float4*)(in + i);
        half4v h = { (_Float16)v.x, (_Float16)v.y, (_Float16)v.z, (_Float16)v.w };
        *(half4v*)(out + i) = h;
    }
}

// ---------------------------------------------------------------------------
// Dense head: out[m] = sigmoid(h2[m,:] . Wd + bd), one wave per row
// ---------------------------------------------------------------------------
__global__ __launch_bounds__(64) void dense_head(const _Float16* __restrict__ h2,
                                                 const float* __restrict__ Wd,
                                                 const float* __restrict__ bd,
                                                 float* __restrict__ out)
{
    const int m = blockIdx.x;
    const int l = threadIdx.x;
    float s = 0.0f;
#pragma unroll
    for (int k = l; k < 1024; k += 64)
        s += (float)h2[(size_t)m * 1024 + k] * Wd[k];
    for (int off = 32; off > 0; off >>= 1) s += __shfl_down(s, off);
    if (l == 0) out[m] = 1.0f / (1.0f + __expf(-(s + bd[0])));
}

// ---------------------------------------------------------------------------

extern "C" void kernel_launch(void* const* d_in, const int* in_sizes, int n_in,
                              void* d_out, int out_size, void* d_ws, size_t ws_size,
                              hipStream_t stream)
{
    const float* x  = (const float*)d_in[0];
    const float* W1 = (const float*)d_in[1];
    const float* U1 = (const float*)d_in[2];
    const float* b1 = (const float*)d_in[3];
    const float* W2 = (const float*)d_in[4];
    const float* U2 = (const float*)d_in[5];
    const float* b2 = (const float*)d_in[6];
    const float* Wd = (const float*)d_in[7];
    const float* bd = (const float*)d_in[8];
    float* out = (float*)d_out;

    char* ws = (char*)d_ws;
    size_t off = 0;
    auto alloc = [&](size_t bytes) {
        char* p = ws + off;
        off = (off + bytes + 255) & ~(size_t)255;
        return p;
    };
    _Float16* xb = (_Float16*)alloc(512ull * 128 * 64 * 2);   // x as f16 (B,T,F)
    _Float16* P1 = (_Float16*)alloc(256ull * 34 * 512 * 2);   // packed layer1
    _Float16* P2 = (_Float16*)alloc(256ull * 64 * 512 * 2);   // packed layer2
    _Float16* h1 = (_Float16*)alloc(2ull * 512 * 1024 * 2);   // ping-pong
    _Float16* h2 = (_Float16*)alloc(2ull * 512 * 1024 * 2);
    float*    c1 = (float*)alloc(512ull * 1024 * 4);
    float*    c2 = (float*)alloc(512ull * 1024 * 4);

    // zero initial state (ws is re-poisoned to 0xAA before every launch)
    hipMemsetAsync(c1, 0, 512ull * 1024 * 4, stream);
    hipMemsetAsync(c2, 0, 512ull * 1024 * 4, stream);
    hipMemsetAsync(h1, 0, 512ull * 1024 * 2, stream);  // slot 0 (read at t=0)
    hipMemsetAsync(h2, 0, 512ull * 1024 * 2, stream);  // slot 0

    cvt_f16<<<4096, 256, 0, stream>>>(x, xb, 512 * 128 * 64);
    pack_weights<<<(256 * 34 * 512 + 255) / 256, 256, 0, stream>>>(W1, U1, 64, 34, P1);
    pack_weights<<<(256 * 64 * 512 + 255) / 256, 256, 0, stream>>>(W2, U2, 1024, 64, P2);

    // 129 pipelined launches: launch s does layer1(s) + layer2(s-1)
    for (int s = 0; s <= 128; ++s) {
        fused_step<<<512, 256, 0, stream>>>(s, xb, P1, P2,
                                            b1, c1, h1, b2, c2, h2);
    }
    // h2(127) lands in slot 0
    dense_head<<<512, 64, 0, stream>>>(h2, Wd, bd, out);
}

// Round 7
// 3900.318 us; speedup vs baseline: 3.9822x; 1.0278x over previous
//
#include <hip/hip_runtime.h>
#include <hip/hip_bf16.h>
#include <cstdint>

// ---------------------------------------------------------------------------
// 2-layer LSTM (B=512, T=128, F=64, H=1024) + dense sigmoid head.
// R7: ZERO-LDS, ZERO-BARRIER step kernel. Both A (activations) and B
// (weights) live in MFMA-fragment granule layout (1 KB granule = 16 rows x
// 32 k, lane-major: lane l -> row base+(l&15), k = kc*32+(l>>4)*8..+7).
// h is WRITTEN by the epilogue directly in granule layout, x is packed once,
// so every fragment load is one contiguous dwordx4/lane from L2. The K-loop
// is a pure register ping-pong (distinct variables - R5 spill lesson) with
// compiler-scheduled fine-grained vmcnt(N): no __syncthreads, no vmcnt(0).
// ---------------------------------------------------------------------------

typedef __attribute__((ext_vector_type(8))) _Float16 half8;
typedef __attribute__((ext_vector_type(4))) float    float4v;

__device__ __forceinline__ float sigf(float x) { return 1.0f / (1.0f + __expf(-x)); }
__device__ __forceinline__ float tanhfast(float x) { return 2.0f * sigf(2.0f * x) - 1.0f; }

static constexpr size_t HPS = 32ull * 32 * 512;   // packed h slot (elems) = 512K

struct FragA { half8 a0[2]; half8 a1[2]; };   // [K0] x two 16-row subtiles
struct FragB { half8 b[2][4]; };              // [K0][gate]

// ---------------------------------------------------------------------------
// Fused pipeline step. Launch s (0..128):
//   blocks [0,256):   layer1 step t=s      (skip when s==128)
//   blocks [256,512): layer2 step t=s-1    (skip when s==0)
// z = [x_t|h] @ [W|U]^T + bias ; gates ; c,h update.
// Block tile 64m x 32n x 4 gates, 4 waves; wave tile 32m x 16n x 4 gates.
// Grid 512 = 2 blocks/CU. XCD = blockIdx%8 = n-tile low bits -> each XCD
// re-reads a fixed packed-weight slice (L2-resident).
// A granule streams: layer1 = [x_packed(t) kc 0..1 | h1_packed kc 0..31];
// layer2 = [h1_packed kc 0..31 | h2_packed kc 0..31]. Segment switch is
// kt-aligned (KC0 even), branch is wave-uniform.
// ---------------------------------------------------------------------------
__global__ __launch_bounds__(256, 2) void fused_step(
    int s,
    const _Float16* __restrict__ xp,   // packed x: ((t*32+mG)*2+kc)*512
    const _Float16* __restrict__ P1,   // packed layer1 weights, KCB=34
    const _Float16* __restrict__ P2,   // packed layer2 weights, KCB=64
    const float* __restrict__ b1, float* __restrict__ c1, _Float16* __restrict__ h1p,
    const float* __restrict__ b2, float* __restrict__ c2, _Float16* __restrict__ h2p)
{
    const int role = blockIdx.x >> 8;        // 0: layer1, 1: layer2
    const int idx  = blockIdx.x & 255;

    const _Float16 *As0, *As1, *Pk;
    const float* bias; float* cs; _Float16* hop;
    int KC0, KCB, KT;
    if (role == 0) {                         // ---- layer 1, step t = s ----
        const int t = s; if (t >= 128) return;
        As0 = xp + (size_t)t * 32768;  KC0 = 2;      // x granules (stride 2/mG)
        As1 = h1p + (size_t)(t & 1) * HPS;           // h1(t-1), stride 32/mG
        Pk = P1; KCB = 34; KT = 17;
        bias = b1; cs = c1;
        hop = h1p + (size_t)(1 - (t & 1)) * HPS;
    } else {                                 // ---- layer 2, step t = s-1 ----
        const int t = s - 1; if (t < 0) return;
        As0 = h1p + (size_t)(1 - (t & 1)) * HPS; KC0 = 32;  // h1(t)
        As1 = h2p + (size_t)(t & 1) * HPS;                  // h2(t-1)
        Pk = P2; KCB = 64; KT = 32;
        bias = b2; cs = c2;
        hop = h2p + (size_t)(1 - (t & 1)) * HPS;
    }

    const int tid = threadIdx.x;
    const int w   = tid >> 6;      // wave 0..3
    const int l   = tid & 63;
    const int q   = l >> 4;
    const int c16 = l & 15;
    const int mh  = w & 1;         // 32-row half
    const int nh  = w >> 1;        // 16-unit half

    const int m0 = (idx >> 5) * 64;      // 8 m-tiles
    const int n0 = (idx & 31) * 32;      // 32 n-tiles (low bits -> XCD slice)
    const int mGa = (m0 >> 4) + mh * 2;  // this wave's first A granule row

    const size_t l8 = (size_t)l * 8;

    // per-gate packed-B granule base (granule row = g*64 + n0/16 + nh)
    const _Float16* bp[4];
#pragma unroll
    for (int g = 0; g < 4; ++g)
        bp[g] = Pk + ((size_t)(g * 64 + (n0 >> 4) + nh) * KCB) * 512 + l8;

    float4v acc[4][2] = {};        // [gate][m-subtile]

    auto loadA = [&](int kt, FragA& f) {
#pragma unroll
        for (int K0 = 0; K0 < 2; ++K0) {
            const int kc = kt * 2 + K0;
            const _Float16* p0 = (kc < KC0)
                ? As0 + ((size_t)(mGa * KC0 + kc)) * 512
                : As1 + ((size_t)(mGa * 32 + (kc - KC0))) * 512;
            const _Float16* p1 = (kc < KC0)
                ? As0 + ((size_t)((mGa + 1) * KC0 + kc)) * 512
                : As1 + ((size_t)((mGa + 1) * 32 + (kc - KC0))) * 512;
            f.a0[K0] = *(const half8*)(p0 + l8);
            f.a1[K0] = *(const half8*)(p1 + l8);
        }
    };
    auto loadB = [&](int kt, FragB& f) {
#pragma unroll
        for (int K0 = 0; K0 < 2; ++K0)
#pragma unroll
            for (int g = 0; g < 4; ++g)
                f.b[K0][g] = *(const half8*)(bp[g] + (size_t)(kt * 2 + K0) * 512);
    };
    auto compute = [&](const FragA& fa, const FragB& fb) {
#pragma unroll
        for (int K0 = 0; K0 < 2; ++K0) {
#pragma unroll
            for (int g = 0; g < 4; ++g) {
                acc[g][0] = __builtin_amdgcn_mfma_f32_16x16x32_f16(fa.a0[K0], fb.b[K0][g], acc[g][0], 0, 0, 0);
                acc[g][1] = __builtin_amdgcn_mfma_f32_16x16x32_f16(fa.a1[K0], fb.b[K0][g], acc[g][1], 0, 0, 0);
            }
        }
    };

    // register ping-pong, DISTINCT variables (no dynamic local indexing)
    FragA fa0, fa1; FragB fb0, fb1;
    loadA(0, fa0); loadB(0, fb0);
    int kt = 0;
    for (; kt + 2 <= KT; kt += 2) {
        loadA(kt + 1, fa1); loadB(kt + 1, fb1);
        compute(fa0, fb0);
        if (kt + 2 < KT) { loadA(kt + 2, fa0); loadB(kt + 2, fb0); }
        compute(fa1, fb1);
    }
    if (kt < KT) compute(fa0, fb0);      // odd-KT tail (layer1: KT=17)

    // ---- fused gate epilogue; h written in A-granule layout ----
    // element (m,n): granule (m>>4, n>>5), lane' = (m&15) | (((n>>3)&3)<<4),
    // byte j = n&7. Here kc = n0>>5 and region bits come from (nh, c16>>3).
    const int ng = n0 + nh * 16 + c16;
    const float bi  = bias[ng];
    const float bff = bias[1024 + ng];
    const float bg  = bias[2048 + ng];
    const float bo  = bias[3072 + ng];
    const int kcH   = n0 >> 5;
    const int laneW = (nh * 2 + (c16 >> 3)) << 4;   // lane' high bits
    const int jW    = c16 & 7;
#pragma unroll
    for (int mt = 0; mt < 2; ++mt) {
        const int mG = (m0 >> 4) + mh * 2 + mt;
        _Float16* hg = hop + ((size_t)(mG * 32 + kcH)) * 512 + (size_t)laneW * 8 + jW;
#pragma unroll
        for (int i = 0; i < 4; ++i) {
            const int m = m0 + mh * 32 + mt * 16 + q * 4 + i;
            const float zi = acc[0][mt][i] + bi;
            const float zf = acc[1][mt][i] + bff;
            const float zg = acc[2][mt][i] + bg;
            const float zo = acc[3][mt][i] + bo;
            const float ig = sigf(zi);
            const float fg = sigf(zf);
            const float gg = tanhfast(zg);
            const float og = sigf(zo);
            const size_t cidx = (size_t)m * 1024 + ng;
            const float cc = fg * cs[cidx] + ig * gg;
            cs[cidx] = cc;
            hg[(q * 4 + i) * 8] = (_Float16)(og * tanhfast(cc));
        }
    }
}

// ---------------------------------------------------------------------------
// Pack [W (KA,4096) | U (K-KA,4096)] fp32 row-major into B-fragment granules:
// out[((ntG*KC + kc)*64 + lane)*8 + j] = f16( src[k][ntG*16+(lane&15)] ),
// k = kc*32 + (lane>>4)*8 + j.
// ---------------------------------------------------------------------------
__global__ void pack_weights(const float* __restrict__ W, const float* __restrict__ U,
                             int KA, int KC, _Float16* __restrict__ out)
{
    const size_t e = (size_t)blockIdx.x * blockDim.x + threadIdx.x;
    const size_t total = (size_t)256 * KC * 512;
    if (e >= total) return;
    const int j    = (int)(e & 7);
    const int lane = (int)((e >> 3) & 63);
    const size_t g = e >> 9;
    const int kc  = (int)(g % KC);
    const int ntG = (int)(g / KC);
    const int col = ntG * 16 + (lane & 15);
    const int k   = kc * 32 + (lane >> 4) * 8 + j;
    const float v = (k < KA) ? W[(size_t)k * 4096 + col]
                             : U[(size_t)(k - KA) * 4096 + col];
    out[e] = (_Float16)v;
}

// ---------------------------------------------------------------------------
// Pack x (B=512, T=128, F=64) fp32 into per-timestep A-granules:
// xp[((t*32+mG)*2+kc)*512 + lane*8 + j] = f16( x[m=mG*16+(lane&15)][t][f] ),
// f = kc*32 + (lane>>4)*8 + j.
// ---------------------------------------------------------------------------
__global__ void pack_x(const float* __restrict__ x, _Float16* __restrict__ xp)
{
    const int e = blockIdx.x * blockDim.x + threadIdx.x;
    if (e >= 512 * 128 * 64) return;
    const int j  = e & 7;
    const int l  = (e >> 3) & 63;
    const int g  = e >> 9;
    const int kc = g & 1;
    const int tm = g >> 1;
    const int mG = tm & 31;
    const int t  = tm >> 5;
    const int m  = mG * 16 + (l & 15);
    const int f  = kc * 32 + (l >> 4) * 8 + j;
    xp[e] = (_Float16)x[((size_t)m * 128 + t) * 64 + f];
}

// ---------------------------------------------------------------------------
// Dense head on packed h2: out[m] = sigmoid(h2[m,:].Wd + bd).
// Block = one granule row (16 m), 64 lanes; lanes l, l^16, l^32 share m=l&15.
// ---------------------------------------------------------------------------
__global__ __launch_bounds__(64) void dense_head(const _Float16* __restrict__ h2p,
                                                 const float* __restrict__ Wd,
                                                 const float* __restrict__ bd,
                                                 float* __restrict__ out)
{
    const int mG = blockIdx.x;
    const int l  = threadIdx.x;
    float s = 0.0f;
    for (int kc = 0; kc < 32; ++kc) {
        half8 f = *(const half8*)(h2p + ((size_t)(mG * 32 + kc)) * 512 + (size_t)l * 8);
        const int kb = kc * 32 + (l >> 4) * 8;
#pragma unroll
        for (int j = 0; j < 8; ++j) s += (float)f[j] * Wd[kb + j];
    }
    s += __shfl_xor(s, 16);
    s += __shfl_xor(s, 32);
    if (l < 16) out[mG * 16 + l] = 1.0f / (1.0f + __expf(-(s + bd[0])));
}

// ---------------------------------------------------------------------------

extern "C" void kernel_launch(void* const* d_in, const int* in_sizes, int n_in,
                              void* d_out, int out_size, void* d_ws, size_t ws_size,
                              hipStream_t stream)
{
    const float* x  = (const float*)d_in[0];
    const float* W1 = (const float*)d_in[1];
    const float* U1 = (const float*)d_in[2];
    const float* b1 = (const float*)d_in[3];
    const float* W2 = (const float*)d_in[4];
    const float* U2 = (const float*)d_in[5];
    const float* b2 = (const float*)d_in[6];
    const float* Wd = (const float*)d_in[7];
    const float* bd = (const float*)d_in[8];
    float* out = (float*)d_out;

    char* ws = (char*)d_ws;
    size_t off = 0;
    auto alloc = [&](size_t bytes) {
        char* p = ws + off;
        off = (off + bytes + 255) & ~(size_t)255;
        return p;
    };
    _Float16* xp  = (_Float16*)alloc(512ull * 128 * 64 * 2);  // packed x
    _Float16* P1  = (_Float16*)alloc(256ull * 34 * 512 * 2);  // packed layer1 W|U
    _Float16* P2  = (_Float16*)alloc(256ull * 64 * 512 * 2);  // packed layer2 W|U
    _Float16* h1p = (_Float16*)alloc(2ull * HPS * 2);         // packed h1 ping-pong
    _Float16* h2p = (_Float16*)alloc(2ull * HPS * 2);         // packed h2 ping-pong
    float*    c1  = (float*)alloc(512ull * 1024 * 4);
    float*    c2  = (float*)alloc(512ull * 1024 * 4);

    // zero initial state (ws is re-poisoned to 0xAA before every launch)
    hipMemsetAsync(c1, 0, 512ull * 1024 * 4, stream);
    hipMemsetAsync(c2, 0, 512ull * 1024 * 4, stream);
    hipMemsetAsync(h1p, 0, HPS * 2, stream);   // slot 0 (read at t=0)
    hipMemsetAsync(h2p, 0, HPS * 2, stream);   // slot 0

    pack_x<<<(512 * 128 * 64 + 255) / 256, 256, 0, stream>>>(x, xp);
    pack_weights<<<(256 * 34 * 512 + 255) / 256, 256, 0, stream>>>(W1, U1, 64, 34, P1);
    pack_weights<<<(256 * 64 * 512 + 255) / 256, 256, 0, stream>>>(W2, U2, 1024, 64, P2);

    // 129 pipelined launches: launch s does layer1(s) + layer2(s-1)
    for (int s = 0; s <= 128; ++s) {
        fused_step<<<512, 256, 0, stream>>>(s, xp, P1, P2,
                                            b1, c1, h1p, b2, c2, h2p);
    }
    // h2(127) lands in slot 0
    dense_head<<<32, 64, 0, stream>>>(h2p, Wd, bd, out);
}

// Round 8
// 3481.872 us; speedup vs baseline: 4.4608x; 1.1202x over previous
//
#include <hip/hip_runtime.h>
#include <hip/hip_bf16.h>
#include <cstdint>

// ---------------------------------------------------------------------------
// 2-layer LSTM (B=512, T=128, F=64, H=1024) + dense sigmoid head.
// R8: L2-traffic-optimized. Wave tile doubled to 64m x 16n x 4 gates
// (0.5 KB loaded per MFMA vs 0.75 in R7 -> ~392 MB/launch vs 588).
// Zero-LDS zero-barrier: all fragments in granule layout (1 KB = 16 rows x
// 32 k, lane-major), loaded as one contiguous dwordx4/lane from L2.
// K-loop: register ping-pong over BK=128 stages (64 MFMA/stage covers L2
// latency at 1 wave/SIMD), distinct FragSet variables (R5 spill lesson).
// Grid 256 x 256thr = 1 block/CU; role interleaved on XCD bits.
// ---------------------------------------------------------------------------

typedef __attribute__((ext_vector_type(8))) _Float16 half8;
typedef __attribute__((ext_vector_type(4))) float    float4v;

__device__ __forceinline__ float sigf(float x) { return 1.0f / (1.0f + __expf(-x)); }
__device__ __forceinline__ float tanhfast(float x) { return 2.0f * sigf(2.0f * x) - 1.0f; }

static constexpr size_t HPS = 32ull * 32 * 512;   // packed h slot (elems)

struct FragSet {          // one BK=128 stage for one wave (128 VGPR)
    half8 A[4][4];        // [msub][kcl]
    half8 B[4][4];        // [kcl][gate]
};

// ---------------------------------------------------------------------------
// Launch s (0..128): role 0 blocks run layer1 step t=s (skip s==128),
// role 1 blocks run layer2 step t=s-1 (skip s==0).
// b = blockIdx.x (0..255): role=(b>>3)&1, tile=((b>>4)<<3)|(b&7) in 0..127.
// tile: m-strip = tile>>5 (4 strips of 128 rows), n-strip = tile&31.
// XCD = b%8 tracks n-strip low bits for both roles -> fixed L2 weight slice.
// Wave w: mh=w&1 (64-row half), nh=w>>1 (16-unit half).
// ---------------------------------------------------------------------------
__global__ __launch_bounds__(256, 1) void fused_step(
    int s,
    const _Float16* __restrict__ xp,   // packed x: ((t*32+mG)*2+kc)*512
    const _Float16* __restrict__ P1,   // packed layer1 weights, KCB=34
    const _Float16* __restrict__ P2,   // packed layer2 weights, KCB=64
    const float* __restrict__ b1, float* __restrict__ c1, _Float16* __restrict__ h1p,
    const float* __restrict__ b2, float* __restrict__ c2, _Float16* __restrict__ h2p)
{
    const int b    = blockIdx.x;
    const int role = (b >> 3) & 1;
    const int tile = ((b >> 4) << 3) | (b & 7);    // 0..127

    const _Float16 *As0, *As1, *Pk;
    const float* bias; float* cs; _Float16* hop;
    int KC0, KCB, KCT;                 // A seg-0 len, B granule stride, total kc
    if (role == 0) {                   // ---- layer 1, step t = s ----
        const int t = s; if (t >= 128) return;
        As0 = xp + (size_t)t * 32768;  KC0 = 2;     // x granules, stride 2/mG
        As1 = h1p + (size_t)(t & 1) * HPS;          // h1(t-1), stride 32/mG
        Pk = P1; KCB = 34; KCT = 34;
        bias = b1; cs = c1;
        hop = h1p + (size_t)(1 - (t & 1)) * HPS;
    } else {                           // ---- layer 2, step t = s-1 ----
        const int t = s - 1; if (t < 0) return;
        As0 = h1p + (size_t)(1 - (t & 1)) * HPS; KC0 = 32;  // h1(t)
        As1 = h2p + (size_t)(t & 1) * HPS;                  // h2(t-1)
        Pk = P2; KCB = 64; KCT = 64;
        bias = b2; cs = c2;
        hop = h2p + (size_t)(1 - (t & 1)) * HPS;
    }

    const int tid = threadIdx.x;
    const int w   = tid >> 6;
    const int l   = tid & 63;
    const int q   = l >> 4;
    const int c16 = l & 15;
    const int mh  = w & 1;             // 64-row half
    const int nh  = w >> 1;            // 16-unit half

    const int m0  = (tile >> 5) * 128;
    const int n0  = (tile & 31) * 32;
    const int mG0 = (m0 >> 4) + mh * 4;    // wave's first A granule (of 4)

    const size_t l8 = (size_t)l * 8;

    const _Float16* bp[4];             // per-gate packed-B granule base
#pragma unroll
    for (int g = 0; g < 4; ++g)
        bp[g] = Pk + ((size_t)(g * 64 + (n0 >> 4) + nh) * KCB) * 512 + l8;

    float4v acc[4][4] = {};            // [gate][msub]

    auto loadS = [&](int st, FragSet& S) {
#pragma unroll
        for (int kcl = 0; kcl < 4; ++kcl) {
            const int kc = st * 4 + kcl;
            const _Float16* ab; size_t astr;
            if (kc < KC0) { ab = As0 + (size_t)kc * 512;         astr = (size_t)KC0 * 512; }
            else          { ab = As1 + (size_t)(kc - KC0) * 512; astr = 32ull * 512; }
            ab += (size_t)mG0 * astr + l8;
#pragma unroll
            for (int ms = 0; ms < 4; ++ms)
                S.A[ms][kcl] = *(const half8*)(ab + (size_t)ms * astr);
#pragma unroll
            for (int g = 0; g < 4; ++g)
                S.B[kcl][g] = *(const half8*)(bp[g] + (size_t)kc * 512);
        }
    };
    auto computeS = [&](const FragSet& S) {
#pragma unroll
        for (int kcl = 0; kcl < 4; ++kcl)
#pragma unroll
            for (int g = 0; g < 4; ++g)
#pragma unroll
                for (int ms = 0; ms < 4; ++ms)
                    acc[g][ms] = __builtin_amdgcn_mfma_f32_16x16x32_f16(
                        S.A[ms][kcl], S.B[kcl][g], acc[g][ms], 0, 0, 0);
    };

    const int NS = KCT >> 2;           // full BK128 stages: 8 (l1) / 16 (l2)
    FragSet S0, S1;                    // DISTINCT variables (no dyn indexing)
    loadS(0, S0);
    for (int st = 0; st + 2 <= NS; st += 2) {
        loadS(st + 1, S1);
        computeS(S0);
        if (st + 2 < NS) loadS(st + 2, S0);
        computeS(S1);
    }
    if (KCT & 3) {                     // layer1 tail: kc 32,33 (from As1)
        half8 At[4][2], Bt[2][4];
#pragma unroll
        for (int kcl = 0; kcl < 2; ++kcl) {
            const int kc = NS * 4 + kcl;
            const _Float16* ab = As1 + (size_t)(kc - KC0) * 512
                               + (size_t)mG0 * (32ull * 512) + l8;
#pragma unroll
            for (int ms = 0; ms < 4; ++ms)
                At[ms][kcl] = *(const half8*)(ab + (size_t)ms * (32ull * 512));
#pragma unroll
            for (int g = 0; g < 4; ++g)
                Bt[kcl][g] = *(const half8*)(bp[g] + (size_t)kc * 512);
        }
#pragma unroll
        for (int kcl = 0; kcl < 2; ++kcl)
#pragma unroll
            for (int g = 0; g < 4; ++g)
#pragma unroll
                for (int ms = 0; ms < 4; ++ms)
                    acc[g][ms] = __builtin_amdgcn_mfma_f32_16x16x32_f16(
                        At[ms][kcl], Bt[kcl][g], acc[g][ms], 0, 0, 0);
    }

    // ---- fused gate epilogue; h written in A-granule layout ----
    const int ng = n0 + nh * 16 + c16;
    const float bi  = bias[ng];
    const float bff = bias[1024 + ng];
    const float bg  = bias[2048 + ng];
    const float bo  = bias[3072 + ng];
    const int kcH   = n0 >> 5;
    const int laneW = (nh * 2 + (c16 >> 3)) << 4;
    const int jW    = c16 & 7;
#pragma unroll
    for (int ms = 0; ms < 4; ++ms) {
        const int mG = mG0 + ms;
        _Float16* hg = hop + ((size_t)(mG * 32 + kcH)) * 512 + (size_t)laneW * 8 + jW;
#pragma unroll
        for (int i = 0; i < 4; ++i) {
            const int m = m0 + mh * 64 + ms * 16 + q * 4 + i;
            const float zi = acc[0][ms][i] + bi;
            const float zf = acc[1][ms][i] + bff;
            const float zg = acc[2][ms][i] + bg;
            const float zo = acc[3][ms][i] + bo;
            const float ig = sigf(zi);
            const float fg = sigf(zf);
            const float gg = tanhfast(zg);
            const float og = sigf(zo);
            const size_t cidx = (size_t)m * 1024 + ng;
            const float cc = fg * cs[cidx] + ig * gg;
            cs[cidx] = cc;
            hg[(q * 4 + i) * 8] = (_Float16)(og * tanhfast(cc));
        }
    }
}

// ---------------------------------------------------------------------------
// Pack [W (KA,4096) | U (K-KA,4096)] fp32 row-major into B-fragment granules.
// ---------------------------------------------------------------------------
__global__ void pack_weights(const float* __restrict__ W, const float* __restrict__ U,
                             int KA, int KC, _Float16* __restrict__ out)
{
    const size_t e = (size_t)blockIdx.x * blockDim.x + threadIdx.x;
    const size_t total = (size_t)256 * KC * 512;
    if (e >= total) return;
    const int j    = (int)(e & 7);
    const int lane = (int)((e >> 3) & 63);
    const size_t g = e >> 9;
    const int kc  = (int)(g % KC);
    const int ntG = (int)(g / KC);
    const int col = ntG * 16 + (lane & 15);
    const int k   = kc * 32 + (lane >> 4) * 8 + j;
    const float v = (k < KA) ? W[(size_t)k * 4096 + col]
                             : U[(size_t)(k - KA) * 4096 + col];
    out[e] = (_Float16)v;
}

// ---------------------------------------------------------------------------
// Pack x (B=512, T=128, F=64) fp32 into per-timestep A-granules.
// ---------------------------------------------------------------------------
__global__ void pack_x(const float* __restrict__ x, _Float16* __restrict__ xp)
{
    const int e = blockIdx.x * blockDim.x + threadIdx.x;
    if (e >= 512 * 128 * 64) return;
    const int j  = e & 7;
    const int l  = (e >> 3) & 63;
    const int g  = e >> 9;
    const int kc = g & 1;
    const int tm = g >> 1;
    const int mG = tm & 31;
    const int t  = tm >> 5;
    const int m  = mG * 16 + (l & 15);
    const int f  = kc * 32 + (l >> 4) * 8 + j;
    xp[e] = (_Float16)x[((size_t)m * 128 + t) * 64 + f];
}

// ---------------------------------------------------------------------------
// Dense head on packed h2: out[m] = sigmoid(h2[m,:].Wd + bd).
// ---------------------------------------------------------------------------
__global__ __launch_bounds__(64) void dense_head(const _Float16* __restrict__ h2p,
                                                 const float* __restrict__ Wd,
                                                 const float* __restrict__ bd,
                                                 float* __restrict__ out)
{
    const int mG = blockIdx.x;
    const int l  = threadIdx.x;
    float s = 0.0f;
    for (int kc = 0; kc < 32; ++kc) {
        half8 f = *(const half8*)(h2p + ((size_t)(mG * 32 + kc)) * 512 + (size_t)l * 8);
        const int kb = kc * 32 + (l >> 4) * 8;
#pragma unroll
        for (int j = 0; j < 8; ++j) s += (float)f[j] * Wd[kb + j];
    }
    s += __shfl_xor(s, 16);
    s += __shfl_xor(s, 32);
    if (l < 16) out[mG * 16 + l] = 1.0f / (1.0f + __expf(-(s + bd[0])));
}

// ---------------------------------------------------------------------------

extern "C" void kernel_launch(void* const* d_in, const int* in_sizes, int n_in,
                              void* d_out, int out_size, void* d_ws, size_t ws_size,
                              hipStream_t stream)
{
    const float* x  = (const float*)d_in[0];
    const float* W1 = (const float*)d_in[1];
    const float* U1 = (const float*)d_in[2];
    const float* b1 = (const float*)d_in[3];
    const float* W2 = (const float*)d_in[4];
    const float* U2 = (const float*)d_in[5];
    const float* b2 = (const float*)d_in[6];
    const float* Wd = (const float*)d_in[7];
    const float* bd = (const float*)d_in[8];
    float* out = (float*)d_out;

    char* ws = (char*)d_ws;
    size_t off = 0;
    auto alloc = [&](size_t bytes) {
        char* p = ws + off;
        off = (off + bytes + 255) & ~(size_t)255;
        return p;
    };
    _Float16* xp  = (_Float16*)alloc(512ull * 128 * 64 * 2);  // packed x
    _Float16* P1  = (_Float16*)alloc(256ull * 34 * 512 * 2);  // packed layer1 W|U
    _Float16* P2  = (_Float16*)alloc(256ull * 64 * 512 * 2);  // packed layer2 W|U
    _Float16* h1p = (_Float16*)alloc(2ull * HPS * 2);         // packed h1 ping-pong
    _Float16* h2p = (_Float16*)alloc(2ull * HPS * 2);         // packed h2 ping-pong
    float*    c1  = (float*)alloc(512ull * 1024 * 4);
    float*    c2  = (float*)alloc(512ull * 1024 * 4);

    // zero initial state (ws is re-poisoned to 0xAA before every launch)
    hipMemsetAsync(c1, 0, 512ull * 1024 * 4, stream);
    hipMemsetAsync(c2, 0, 512ull * 1024 * 4, stream);
    hipMemsetAsync(h1p, 0, HPS * 2, stream);   // slot 0 (read at t=0)
    hipMemsetAsync(h2p, 0, HPS * 2, stream);   // slot 0

    pack_x<<<(512 * 128 * 64 + 255) / 256, 256, 0, stream>>>(x, xp);
    pack_weights<<<(256 * 34 * 512 + 255) / 256, 256, 0, stream>>>(W1, U1, 64, 34, P1);
    pack_weights<<<(256 * 64 * 512 + 255) / 256, 256, 0, stream>>>(W2, U2, 1024, 64, P2);

    // 129 pipelined launches: launch s does layer1(s) + layer2(s-1)
    for (int s = 0; s <= 128; ++s) {
        fused_step<<<256, 256, 0, stream>>>(s, xp, P1, P2,
                                            b1, c1, h1p, b2, c2, h2p);
    }
    // h2(127) lands in slot 0
    dense_head<<<32, 64, 0, stream>>>(h2p, Wd, bd, out);
}